// Round 6
// baseline (353.725 us; speedup 1.0000x reference)
//
#include <hip/hip_runtime.h>

// DetectionLoss: B=16, A=65536, T=32, C=21.
// R14: (a) REVERT R13's conf-LDS-staging (regressed 55->71us: serialized the
// kernel + dropped occupancy; the stride-84 gather overlapped fine). main is
// back to R12's structure (measured 54-57us) with one kept tweak: neg
// cmax == 1.0f exactly (c[argmax]=exp(0)). (b) tailA is FOLDED into main as a
// last-block-per-image epilogue (ctrA counter + threadfence release/acquire,
// same pattern as tailC's final average) -> tailA overlaps main's other
// images and one graph node disappears.
// Graph: memset, main(+A), tailB, tailC.

#define AN 65536
#define BN 16
#define TN 32
#define CN 21
#define NBA 2048     // anchor/cell L1 bins = focal bits >> 20
#define LCAPG (2 * 65536)   // global per-image cell-list capacity
#define LCAP 10240       // LDS-cached list capacity (40 KB)
#define CHUNK 256
#define BUFC (CHUNK * CN)   // 5376 staged cells max per chunk

struct BlockAcc { float pos_sum; float bbox_sum; unsigned np; unsigned nn; };
struct ImgParams { double pos; double bbox; unsigned np, nn, k, ve, act; };

// ---------- shared math: bit-identical across kernels (_rn-pinned, shared fns) ----------
__device__ __forceinline__ float box_area(float4 B) {
    return __fmul_rn(__fsub_rn(B.z, B.x), __fsub_rn(B.w, B.y));
}
__device__ __forceinline__ float iou_rcp(float4 A, float aa, float4 T, float ta) {
    float x1 = fmaxf(A.x, T.x), y1 = fmaxf(A.y, T.y);
    float x2 = fminf(A.z, T.z), y2 = fminf(A.w, T.w);
    float inter = __fmul_rn(fmaxf(__fsub_rn(x2, x1), 0.f), fmaxf(__fsub_rn(y2, y1), 0.f));
    float den = __fadd_rn(__fsub_rn(__fadd_rn(aa, ta), inter), 1e-6f);
    return __fmul_rn(inter, __builtin_amdgcn_rcpf(den));
}
__device__ __forceinline__ float row_prep_vals(float* __restrict__ c) {
    float m1[10];
#pragma unroll
    for (int j = 0; j < 10; ++j) m1[j] = fmaxf(c[j], c[j + 10]);
    float m2[5];
#pragma unroll
    for (int j = 0; j < 5; ++j) m2[j] = fmaxf(m1[j], m1[j + 5]);
    float ma = fmaxf(m2[0], m2[1]), mb = fmaxf(m2[2], m2[3]);
    float m = fmaxf(fmaxf(ma, mb), fmaxf(m2[4], c[20]));
#pragma unroll
    for (int j = 0; j < CN; ++j) c[j] = __expf(__fsub_rn(c[j], m));
    float s1[10];
#pragma unroll
    for (int j = 0; j < 10; ++j) s1[j] = __fadd_rn(c[j], c[j + 10]);
    float s2[5];
#pragma unroll
    for (int j = 0; j < 5; ++j) s2[j] = __fadd_rn(s1[j], s1[j + 5]);
    float sa = __fadd_rn(s2[0], s2[1]), sb = __fadd_rn(s2[2], s2[3]);
    float s = __fadd_rn(__fadd_rn(sa, sb), __fadd_rn(s2[4], c[20]));
    return __builtin_amdgcn_rcpf(s);
}
__device__ __forceinline__ float row_prep(const float* __restrict__ row, float* __restrict__ c) {
#pragma unroll
    for (int j = 0; j < CN; ++j) c[j] = row[j];
    return row_prep_vals(c);
}
__device__ __forceinline__ float cell_focal(float cexp, float inv, bool cellpos) {
    float p = __fmul_rn(cexp, inv);
    float pt = cellpos ? p : __fsub_rn(1.0f, p);
    float af = cellpos ? 0.25f : 0.75f;
    float om = __fsub_rn(1.0f, pt);
    float lg = __logf(fmaxf(pt, 1e-6f));
    return __fmul_rn(__fmul_rn(__fmul_rn(-af, om), om), lg);
}
__device__ __forceinline__ unsigned focal_bits(float fo) {
    unsigned bits = __float_as_uint(fo);
    if (bits == 0x80000000u) bits = 0u;   // canonicalize -0.0
    return bits;
}
__device__ __forceinline__ float bbox_per(float4 b1, float4 b2) {
    float x1 = fmaxf(b1.x, b2.x), y1 = fmaxf(b1.y, b2.y);
    float x2 = fminf(b1.z, b2.z), y2 = fminf(b1.w, b2.w);
    float inter = fmaxf(x2 - x1, 0.f) * fmaxf(y2 - y1, 0.f);
    float a1 = (b1.z - b1.x) * (b1.w - b1.y);
    float a2 = (b2.z - b2.x) * (b2.w - b2.y);
    float un = a1 + a2 - inter;
    float iou = inter / (un + 1e-6f);
    float ex1 = fminf(b1.x, b2.x), ey1 = fminf(b1.y, b2.y);
    float ex2 = fmaxf(b1.z, b2.z), ey2 = fmaxf(b1.w, b2.w);
    float enc = (ex2 - ex1) * (ey2 - ey1);
    float giou = iou - (enc - un) / (enc + 1e-6f);
    float gl = 1.0f - giou;
    float l1 = 0.f, d, ad;
    d = b1.x - b2.x; ad = fabsf(d); l1 += (ad < 1.f) ? (0.5f * d * d) : (ad - 0.5f);
    d = b1.y - b2.y; ad = fabsf(d); l1 += (ad < 1.f) ? (0.5f * d * d) : (ad - 0.5f);
    d = b1.z - b2.z; ad = fabsf(d); l1 += (ad < 1.f) ? (0.5f * d * d) : (ad - 0.5f);
    d = b1.w - b2.w; ad = fabsf(d); l1 += (ad < 1.f) ? (0.5f * d * d) : (ad - 0.5f);
    return gl + 0.5f * (l1 * 0.25f);
}
__device__ __forceinline__ unsigned mbcnt64(unsigned long long m) {
    return __builtin_amdgcn_mbcnt_hi((unsigned)(m >> 32),
           __builtin_amdgcn_mbcnt_lo((unsigned)m, 0u));
}

// ---------- fused main: match + force-argmax + focal + anchor hist + tailA epilogue ----------
__global__ __launch_bounds__(256) void main_kernel(
    const float* __restrict__ conf, const float4* __restrict__ bboxp,
    const float4* __restrict__ anchors, const float4* __restrict__ tboxes,
    const int* __restrict__ tlabels,
    unsigned long long* __restrict__ gbest,
    unsigned* __restrict__ ahist, unsigned* __restrict__ maxb,
    BlockAcc* __restrict__ blockAcc,
    ImgParams* __restrict__ params, unsigned* __restrict__ ctrA)
{
    __shared__ float4 tbS[TN];
    __shared__ int tlS[TN];
    __shared__ float taS[TN];
    __shared__ float iouS[16][260];        // IoU half-matrix; reused by epilogue
    __shared__ unsigned ahp[NBA / 2];      // packed 2 bins/u32
    __shared__ float pbV[TN][16];
    __shared__ int   pbA[TN][16];
    __shared__ float rF[2][4];
    __shared__ unsigned rI[2][4];
    // epilogue scalars
    __shared__ double sdblA[8];
    __shared__ unsigned sunsA[8];
    __shared__ double s_pos, s_bbox;
    __shared__ unsigned s_np, s_nn, s_k, s_act, s_ve, sFlagS;

    int b = blockIdx.y, tid = threadIdx.x;
    int a = blockIdx.x * 256 + tid;
    for (int i = tid; i < NBA / 2; i += 256) ahp[i] = 0u;
    if (tid < TN) {
        float4 T = tboxes[b * TN + tid];
        tbS[tid] = T; tlS[tid] = tlabels[b * TN + tid]; taS[tid] = box_area(T);
    }
    float4 ab = anchors[a];
    float aa = box_area(ab);
    __syncthreads();

    // phases 1+2 chunked over targets (2 x 16): per-anchor running max
    // (ascending t, strict >) + per-target block-best via 16 partials of 16.
    float best = -1.0f; int bt = 0;
#pragma unroll
    for (int h = 0; h < 2; ++h) {
#pragma unroll
        for (int t2 = 0; t2 < 16; ++t2) {
            int t = h * 16 + t2;
            float iou = iou_rcp(ab, aa, tbS[t], taS[t]);
            iouS[t2][tid] = iou;
            if (iou > best) { best = iou; bt = t; }   // strict >: first occurrence
        }
        __syncthreads();
        {
            int t2 = tid & 15, pp = tid >> 4;
            const float4* rp = (const float4*)(&iouS[t2][pp * 16]);
            float bv = -1.f; int ba = 0;
#pragma unroll
            for (int q = 0; q < 4; ++q) {
                float4 v4 = rp[q];
                int i0 = pp * 16 + q * 4;
                if (v4.x > bv) { bv = v4.x; ba = i0 + 0; }
                if (v4.y > bv) { bv = v4.y; ba = i0 + 1; }
                if (v4.z > bv) { bv = v4.z; ba = i0 + 2; }
                if (v4.w > bv) { bv = v4.w; ba = i0 + 3; }
            }
            pbV[h * 16 + t2][pp] = bv; pbA[h * 16 + t2][pp] = ba;
        }
        __syncthreads();   // protect iouS reuse by next chunk / epilogue
    }
    if (tid < TN) {
        float bv = -1.f; int ba = 0;
#pragma unroll
        for (int pp = 0; pp < 16; ++pp) {
            float v = pbV[tid][pp];
            if (v > bv) { bv = v; ba = pbA[tid][pp]; }   // ascending anchor ranges
        }
        unsigned ga = blockIdx.x * 256 + (unsigned)ba;
        unsigned long long key =
            (((unsigned long long)__float_as_uint(bv)) << 32) | (unsigned long long)(unsigned)(~ga);
        atomicMax(&gbest[b * TN + tid], key);   // tie -> smaller anchor idx
    }

    // phase 3: focal (threshold classification; forced anchors fixed in epilogue)
    size_t idx = (size_t)b * AN + a;
    bool posA = best >= 0.5f;
    bool negA = best < 0.4f;
    float fs = 0.f, bper = 0.f;
    unsigned mbenc = 0u;
    if (posA || negA) {
        float c[CN];
        float inv = row_prep(conf + idx * CN, c);
        if (posA) {
            int label = tlS[bt];
#pragma unroll
            for (int j = 0; j < CN; ++j) fs += cell_focal(c[j], inv, j == label);
            bper = bbox_per(bboxp[idx], tbS[bt]);
        } else {
            // neg: max_j focal_j == focal(max_j c_j), and max_j c_j == 1.0f
            // exactly (c[argmax] = exp(x_max - m) = exp(0); others <= 1.0f).
            float fo = cell_focal(1.0f, inv, false);
            unsigned mb = focal_bits(fo);
            mbenc = (mb << 1) | 1u;
            unsigned bin = mb >> 20;
            atomicAdd(&ahp[bin >> 1], 1u << ((bin & 1) << 4));
        }
    }
    maxb[idx] = mbenc;

    // block reduce {pos_sum, bbox_sum, np, nn} -> plain store
    float vpos = posA ? fs : 0.f, vb = bper;
    unsigned inp = posA ? 1u : 0u, inn = negA ? 1u : 0u;
#pragma unroll
    for (int off = 32; off; off >>= 1) {
        vpos += __shfl_down(vpos, off, 64);
        vb   += __shfl_down(vb,   off, 64);
        inp  += __shfl_down(inp,  off, 64);
        inn  += __shfl_down(inn,  off, 64);
    }
    int wv = tid >> 6, ln = tid & 63;
    if (ln == 0) { rF[0][wv] = vpos; rF[1][wv] = vb; rI[0][wv] = inp; rI[1][wv] = inn; }
    __syncthreads();
    if (tid == 0) {
        BlockAcc ba2;
        ba2.pos_sum = rF[0][0] + rF[0][1] + rF[0][2] + rF[0][3];
        ba2.bbox_sum = rF[1][0] + rF[1][1] + rF[1][2] + rF[1][3];
        ba2.np = rI[0][0] + rI[0][1] + rI[0][2] + rI[0][3];
        ba2.nn = rI[1][0] + rI[1][1] + rI[1][2] + rI[1][3];
        blockAcc[b * 256 + blockIdx.x] = ba2;
    }
    for (int i = tid; i < NBA / 2; i += 256) {
        unsigned v = ahp[i];
        if (v) {
            if (v & 0xFFFFu) atomicAdd(&ahist[b * NBA + 2 * i], v & 0xFFFFu);
            if (v >> 16)     atomicAdd(&ahist[b * NBA + 2 * i + 1], v >> 16);
        }
    }
    __syncthreads();   // all this block's global ops drained (vmcnt) before release

    // ---- embedded tailA: last finishing block of image b (release/acquire) ----
    if (tid == 0) {
        __threadfence();                                    // release this block's writes
        unsigned prev = atomicAdd(&ctrA[b * 16], 1u);
        sFlagS = (prev == (unsigned)(AN / 256) - 1u) ? 1u : 0u;
    }
    __syncthreads();
    if (!sFlagS) return;
    __threadfence();                                        // acquire other blocks' writes

    // carve epilogue LDS from the dead iouS buffer
    unsigned* histL = (unsigned*)&iouS[0][0];   // 2048
    unsigned* scanL = histL + 2048;             // 256
    float*    dpsL  = (float*)(scanL + 256);    // 32
    float*    dbbL  = dpsL + TN;                // 32
    int*      dnpL  = (int*)(dbbL + TN);        // 32
    int*      dnnL  = dnpL + TN;                // 32
    unsigned* gaL   = (unsigned*)(dnnL + TN);   // 32  (total 9856B <= 16640B)

    for (int i = tid; i < NBA; i += 256) histL[i] = ahist[b * NBA + i];
    if (tid < TN) {
        gaL[tid] = ~(unsigned)(gbest[b * TN + tid] & 0xFFFFFFFFull);
        dpsL[tid] = 0.f; dbbL[tid] = 0.f; dnpL[tid] = 0; dnnL[tid] = 0;
    }
    __syncthreads();

    // phase A: force-match fix (<=32 anchors)
    if (tid < TN) {
        bool doit = true;
        unsigned ga = gaL[tid];
        for (int u = 0; u < tid; ++u) if (gaL[u] == ga) doit = false;   // dedupe
        if (doit) {
            size_t idx2 = (size_t)b * AN + ga;
            float4 ab2 = anchors[ga];
            float aa2 = box_area(ab2);
            float best2 = -1.f; int bt2 = 0;
#pragma unroll
            for (int t = 0; t < TN; ++t) {
                float iou = iou_rcp(ab2, aa2, tbS[t], taS[t]);   // bit-identical
                if (iou > best2) { best2 = iou; bt2 = t; }
            }
            if (best2 < 0.5f) {
                int label = tlS[bt2];
                float c2[CN];
                float inv2 = row_prep(conf + idx2 * CN, c2);
                float fsv = 0.f;
#pragma unroll
                for (int j = 0; j < CN; ++j) fsv += cell_focal(c2[j], inv2, j == label);
                dpsL[tid] = fsv;
                dbbL[tid] = bbox_per(bboxp[idx2], tbS[bt2]);
                dnpL[tid] = 1;
                if (best2 < 0.4f) {   // was counted neg: undo
                    unsigned enc = maxb[idx2];
                    atomicSub(&histL[enc >> 21], 1u);
                    maxb[idx2] = 0u;
                    dnnL[tid] = -1;
                }
            }
        }
    }
    __syncthreads();

    // phase B: totals (256 threads, 1 BlockAcc each; same shuffle tree/order)
    {
        BlockAcc ba3 = blockAcc[b * 256 + tid];
        double ps = (double)ba3.pos_sum, bs = (double)ba3.bbox_sum;
        unsigned np = ba3.np, nn = ba3.nn;
#pragma unroll
        for (int off = 32; off; off >>= 1) {
            ps += __shfl_down(ps, off, 64);
            bs += __shfl_down(bs, off, 64);
            np += __shfl_down(np, off, 64);
            nn += __shfl_down(nn, off, 64);
        }
        if (ln == 0) { sdblA[wv] = ps; sdblA[4 + wv] = bs; sunsA[wv] = np; sunsA[4 + wv] = nn; }
    }
    __syncthreads();
    if (tid == 0) {
        double dp = 0, db = 0; int cp = 0, cn = 0;
        for (int i = 0; i < TN; ++i) { dp += dpsL[i]; db += dbbL[i]; cp += dnpL[i]; cn += dnnL[i]; }
        s_pos = sdblA[0] + sdblA[1] + sdblA[2] + sdblA[3] + dp;
        s_bbox = sdblA[4] + sdblA[5] + sdblA[6] + sdblA[7] + db;
        unsigned NP = (unsigned)((int)(sunsA[0] + sunsA[1] + sunsA[2] + sunsA[3]) + cp);
        unsigned NN = (unsigned)((int)(sunsA[4] + sunsA[5] + sunsA[6] + sunsA[7]) + cn);
        s_np = NP; s_nn = NN;
        unsigned k = min(3u * NP, NN);
        s_k = k;
        s_act = (NN > 0 && k > 0) ? 1u : 0u;
        s_ve = 0u;
    }
    __syncthreads();

    if (s_act) {
        unsigned k = s_k;
        // phase C: anchor-max threshold (2048 bins, 8/thread, suffix scan)
        unsigned l8[8], cc = 0;
#pragma unroll
        for (int q = 0; q < 8; ++q) { l8[q] = histL[tid * 8 + q]; cc += l8[q]; }
        scanL[tid] = cc;
        __syncthreads();
        for (int off = 1; off < 256; off <<= 1) {
            unsigned v = (tid + off < 256) ? scanL[tid + off] : 0u;
            __syncthreads();
            scanL[tid] += v;
            __syncthreads();
        }
        {
            unsigned above = (tid < 255) ? scanL[tid + 1] : 0u;
            if (above < k && above + cc >= k) {
                unsigned a2 = above;
                for (int q = 7; q >= 0; --q) {
                    unsigned bc = l8[q];
                    if (a2 + bc >= k) { s_ve = ((unsigned)(tid * 8 + q) << 21) | 1u; break; }
                    a2 += bc;
                }
            }
        }
        __syncthreads();
    }
    if (tid == 0) {
        ImgParams P;
        P.pos = s_pos; P.bbox = s_bbox;
        P.np = s_np; P.nn = s_nn; P.k = s_k; P.ve = s_ve; P.act = s_act;
        params[b] = P;
    }
}

// ---------- tailB: parallel compact + focal rows ONCE -> cell-value list ----------
// grid (64, BN) x 256 threads: each block owns 1024 anchors of one image.
// LDS-staged append: cells collected in bufS, ONE global atomic per chunk.
__global__ __launch_bounds__(256) void tailB_kernel(
    const float* __restrict__ conf, const unsigned* __restrict__ maxb,
    const ImgParams* __restrict__ params,
    float* __restrict__ list, unsigned* __restrict__ listCnt)
{
    __shared__ int candS[1024];
    __shared__ unsigned bufS[BUFC];
    __shared__ unsigned s_cnt, s_bcnt, s_gbase;
    int b = blockIdx.y, tid = threadIdx.x;
    unsigned act = params[b].act;
    if (!act) return;
    unsigned ve = params[b].ve;
    unsigned vbits = ve >> 1;
    int base = blockIdx.x * 1024;

    if (tid == 0) s_cnt = 0u;
    __syncthreads();

    const uint4* mb4 = (const uint4*)(maxb + (size_t)b * AN + base);
    uint4 m4 = mb4[tid];
    unsigned c0 = (m4.x >= ve), c1 = (m4.y >= ve), c2 = (m4.z >= ve), c3 = (m4.w >= ve);
    unsigned cnt = c0 + c1 + c2 + c3;
    unsigned pos = 0;
    if (cnt) pos = atomicAdd(&s_cnt, cnt);
    int a0 = base + tid * 4;
    if (c0) candS[pos++] = a0 + 0;
    if (c1) candS[pos++] = a0 + 1;
    if (c2) candS[pos++] = a0 + 2;
    if (c3) candS[pos++] = a0 + 3;
    __syncthreads();
    unsigned n = s_cnt;

    for (unsigned cbase = 0; cbase < n; cbase += CHUNK) {
        if (tid == 0) s_bcnt = 0u;
        __syncthreads();
        unsigned i = cbase + tid;
        if (i < n) {
            int a = candS[i];
            size_t idx = (size_t)b * AN + a;
            float c[CN];
            float inv = row_prep(conf + idx * CN, c);
#pragma unroll
            for (int j = 0; j < CN; ++j) {
                float fo = cell_focal(c[j], inv, false);
                unsigned bits = focal_bits(fo);
                bool hit = bits >= vbits;
                unsigned long long msk = __ballot(hit);
                if (hit) {
                    unsigned pre = mbcnt64(msk);
                    unsigned bb = 0;
                    if (pre == 0) bb = atomicAdd(&s_bcnt, (unsigned)__popcll(msk));
                    bb = __shfl(bb, (int)(__ffsll((long long)msk) - 1), 64);
                    bufS[bb + pre] = bits;   // canonicalized focal bits
                }
            }
        }
        __syncthreads();
        unsigned ccnt = s_bcnt;
        if (ccnt) {
            if (tid == 0) s_gbase = atomicAdd(&listCnt[b * 16], ccnt);  // 64B-padded counter
            __syncthreads();
            unsigned gb = s_gbase;
            for (unsigned j2 = tid; j2 < ccnt; j2 += 256) {
                unsigned p = gb + j2;
                if (p < (unsigned)LCAPG)
                    list[(size_t)b * LCAPG + p] = __uint_as_float(bufS[j2]);
            }
        }
        __syncthreads();
    }
}

// ---------- tailC: top-k select over compact list + per-image result + average ----------
__global__ __launch_bounds__(1024) void tailC_kernel(
    const float* __restrict__ list, const unsigned* __restrict__ listCnt,
    const ImgParams* __restrict__ params,
    double* __restrict__ imgRes, unsigned* __restrict__ ctr,
    float* __restrict__ out)
{
    __shared__ float lcache[LCAP];      // 40 KB
    __shared__ unsigned hist[4096];
    __shared__ unsigned scan_[1024];
    __shared__ double sdbl[16];
    __shared__ double s_sumAbove;
    __shared__ unsigned s_b1, s_rem, s_b2, s_rem2, s_b3, s_rem3;

    int b = blockIdx.x, tid = threadIdx.x;
    int wv = tid >> 6, ln = tid & 63;
    ImgParams P = params[b];
    double topk = 0.0;

    if (P.act) {
        unsigned n = min(listCnt[b * 16], (unsigned)LCAPG);
        const float* gl = list + (size_t)b * LCAPG;
        bool inL = (n <= (unsigned)LCAP);
        if (inL) for (unsigned i = tid; i < n; i += 1024) lcache[i] = gl[i];
        if (tid == 0) { s_b1 = 0; s_rem = 0; s_b3 = 0; s_rem3 = 0; }
        for (int i = tid; i < 4096; i += 1024) hist[i] = 0u;
        __syncthreads();

        // pass 0: 2048-bin hist over top bits (focal >= 0 -> bits>>20 < 2048)
        for (unsigned i = tid; i < n; i += 1024) {
            unsigned bits = __float_as_uint(inL ? lcache[i] : gl[i]);
            atomicAdd(&hist[bits >> 20], 1u);
        }
        __syncthreads();

        // select b1 (suffix scan, 2 bins/thread)
        unsigned lc0 = hist[tid * 2], lc1 = hist[tid * 2 + 1];
        unsigned cc = lc0 + lc1;
        scan_[tid] = cc;
        __syncthreads();
        for (int off = 1; off < 1024; off <<= 1) {
            unsigned v = (tid + off < 1024) ? scan_[tid + off] : 0u;
            __syncthreads();
            scan_[tid] += v;
            __syncthreads();
        }
        {
            unsigned total = scan_[0];
            unsigned above = (tid < 1023) ? scan_[tid + 1] : 0u;
            unsigned r = min(P.k, total);
            if (r > 0 && above < r && above + cc >= r) {
                if (above + lc1 >= r) { s_b1 = (unsigned)(tid * 2 + 1); s_rem = r - above; }
                else { s_b1 = (unsigned)(tid * 2); s_rem = r - above - lc1; }
            }
        }
        __syncthreads();
        unsigned b1 = s_b1, rem = s_rem;

        // pass 1: sumAbove (hi > b1) + 12-bit sub-hist for hi == b1
        for (int i = tid; i < 4096; i += 1024) hist[i] = 0u;
        __syncthreads();
        double sA = 0.0;
        for (unsigned i = tid; i < n; i += 1024) {
            float v = inL ? lcache[i] : gl[i];
            unsigned bits = __float_as_uint(v);
            unsigned hi = bits >> 20;
            if (hi > b1) sA += (double)v;
            else if (hi == b1) atomicAdd(&hist[(bits >> 8) & 0xFFFu], 1u);
        }
#pragma unroll
        for (int off = 32; off; off >>= 1) sA += __shfl_down(sA, off, 64);
        if (ln == 0) sdbl[wv] = sA;
        __syncthreads();
        if (tid == 0) {
            double tt = 0;
            for (int w = 0; w < 16; ++w) tt += sdbl[w];
            s_sumAbove = tt;
        }
        __syncthreads();
        double sumAbove = s_sumAbove;

        if (rem == 0) {
            topk = sumAbove;
        } else {
            // select b2 from 4096-bin hist (4 bins/thread)
            unsigned l4[4], cc4 = 0;
#pragma unroll
            for (int q = 0; q < 4; ++q) { l4[q] = hist[tid * 4 + q]; cc4 += l4[q]; }
            scan_[tid] = cc4;
            __syncthreads();
            for (int off = 1; off < 1024; off <<= 1) {
                unsigned v = (tid + off < 1024) ? scan_[tid + off] : 0u;
                __syncthreads();
                scan_[tid] += v;
                __syncthreads();
            }
            {
                unsigned total = scan_[0];
                unsigned above = (tid < 1023) ? scan_[tid + 1] : 0u;
                unsigned r = min(rem, total);
                if (above < r && above + cc4 >= r) {
                    unsigned a2 = above;
                    for (int i = 3; i >= 0; --i) {
                        unsigned bc = l4[i];
                        if (a2 + bc >= r) { s_b2 = (unsigned)(tid * 4 + i); s_rem2 = r - a2; break; }
                        a2 += bc;
                    }
                }
            }
            __syncthreads();
            unsigned b2 = s_b2, rem2 = s_rem2;
            if (tid < 256) hist[tid] = 0u;
            __syncthreads();

            // pass 2: sMid (sub > b2) + 8-bit hist for sub == b2
            double sMid = 0.0;
            for (unsigned i = tid; i < n; i += 1024) {
                float v = inL ? lcache[i] : gl[i];
                unsigned bits = __float_as_uint(v);
                if ((bits >> 20) != b1) continue;
                unsigned sub = (bits >> 8) & 0xFFFu;
                if (sub > b2) sMid += (double)v;
                else if (sub == b2) atomicAdd(&hist[bits & 0xFFu], 1u);
            }
            __syncthreads();
            if (tid < 256) scan_[tid] = hist[tid];
            __syncthreads();
            for (int off = 1; off < 256; off <<= 1) {
                unsigned v = 0;
                if (tid < 256 && tid + off < 256) v = scan_[tid + off];
                __syncthreads();
                if (tid < 256) scan_[tid] += v;
                __syncthreads();
            }
            if (tid < 256) {
                unsigned above8 = (tid < 255) ? scan_[tid + 1] : 0u;
                unsigned c8 = hist[tid];
                if (above8 < rem2 && above8 + c8 >= rem2) { s_b3 = (unsigned)tid; s_rem3 = rem2 - above8; }
            }
            __syncthreads();
            unsigned b3 = s_b3, rem3 = s_rem3;

            // pass 3: s3 for (b1,b2, low > b3)
            double s3 = 0.0;
            for (unsigned i = tid; i < n; i += 1024) {
                float v = inL ? lcache[i] : gl[i];
                unsigned bits = __float_as_uint(v);
                if ((bits >> 20) == b1 && ((bits >> 8) & 0xFFFu) == b2 && (bits & 0xFFu) > b3)
                    s3 += (double)v;
            }
            double tot = sMid + s3;
#pragma unroll
            for (int off = 32; off; off >>= 1) tot += __shfl_down(tot, off, 64);
            if (ln == 0) sdbl[wv] = tot;
            __syncthreads();
            if (tid == 0) {
                double totAll = 0;
                for (int w = 0; w < 16; ++w) totAll += sdbl[w];
                unsigned vb3 = (b1 << 20) | (b2 << 8) | b3;
                topk = sumAbove + totAll + (double)rem3 * (double)__uint_as_float(vb3);
            }
        }
    }

    // ---- per-image result + last-block average ----
    if (tid == 0) {
        double confl;
        if (P.act) confl = (P.pos + topk) / (double)max(P.np + P.k, 1u);
        else       confl = P.pos / (double)max(P.np, 1u);
        imgRes[b * 2 + 0] = confl;
        imgRes[b * 2 + 1] = P.bbox / (double)max(P.np, 1u);
        __threadfence();
        unsigned prev = atomicAdd(ctr, 1u);
        if (prev == BN - 1) {
            __threadfence();
            double cs = 0, bs = 0;
            for (int i = 0; i < BN; ++i) { cs += imgRes[i * 2]; bs += imgRes[i * 2 + 1]; }
            cs /= BN; bs /= BN;
            out[0] = (float)(cs + bs);
            out[1] = (float)cs;
            out[2] = (float)bs;
        }
    }
}

extern "C" void kernel_launch(void* const* d_in, const int* in_sizes, int n_in,
                              void* d_out, int out_size, void* d_ws, size_t ws_size,
                              hipStream_t stream)
{
    (void)in_sizes; (void)n_in; (void)out_size; (void)ws_size;
    const float*  conf    = (const float*)d_in[0];
    const float4* bboxp   = (const float4*)d_in[1];
    const float4* anchors = (const float4*)d_in[2];
    const float4* tboxes  = (const float4*)d_in[3];
    const int*    tlabels = (const int*)d_in[4];
    float* out = (float*)d_out;
    char* ws = (char*)d_ws;
    size_t off = 0;
    auto alloc = [&](size_t bytes) -> void* {
        void* p = (void*)(ws + off);
        off = (off + bytes + 255) & ~(size_t)255;
        return p;
    };
    unsigned*  maxb     = (unsigned*)alloc((size_t)BN * AN * 4);
    float*     list     = (float*)alloc((size_t)BN * LCAPG * 4);
    BlockAcc*  blockAcc = (BlockAcc*)alloc((size_t)BN * 256 * sizeof(BlockAcc));
    double*    imgRes   = (double*)alloc((size_t)BN * 2 * 8);
    ImgParams* params   = (ImgParams*)alloc((size_t)BN * sizeof(ImgParams));
    size_t zstart = off;
    unsigned long long* gbest = (unsigned long long*)alloc((size_t)BN * TN * 8);
    unsigned* ahist   = (unsigned*)alloc((size_t)BN * NBA * 4);
    unsigned* ctr     = (unsigned*)alloc(256);
    unsigned* listCnt = (unsigned*)alloc((size_t)BN * 16 * 4);   // 64B stride per image
    unsigned* ctrA    = (unsigned*)alloc((size_t)BN * 16 * 4);   // 64B stride per image
    size_t zbytes = off - zstart;
    hipMemsetAsync(ws + zstart, 0, zbytes, stream);

    dim3 gridA(AN / 256, BN);
    main_kernel<<<gridA, 256, 0, stream>>>(conf, bboxp, anchors, tboxes, tlabels,
                                           gbest, ahist, maxb, blockAcc, params, ctrA);
    tailB_kernel<<<dim3(64, BN), 256, 0, stream>>>(conf, maxb, params, list, listCnt);
    tailC_kernel<<<BN, 1024, 0, stream>>>(list, listCnt, params, imgRes, ctr, out);
}

// Round 7
// 201.875 us; speedup vs baseline: 1.7522x; 1.7522x over previous
//
#include <hip/hip_runtime.h>

// DetectionLoss: B=16, A=65536, T=32, C=21.
// R15: REVERT R14's tailA-fold (device-scope __threadfence release in all
// 4096 blocks -> per-XCD L2 writebacks, 229us main; lesson: cross-workgroup
// fences only in O(BN) blocks). Back to R12's proven 4-dispatch structure
// (202.6us total, main 54-57us) plus three bit-identical tweaks:
// (a) neg cmax == 1.0f exactly (c[argmax]=exp(0); absmax-0 proven R13/R14),
// (b) phase-2 reader layout 8x32/tid<128 (1.1M vs 2.7M bank conflicts, R13),
// (c) conf-row loads vectorized via aligned(4) float4 (global_load_dwordx4
//     at 4B align; 21 loads -> 6) in main/tailA/tailB via shared row_prep.
// Graph: memset, main, tailA, tailB, tailC.

#define AN 65536
#define BN 16
#define TN 32
#define CN 21
#define NBA 2048     // anchor/cell L1 bins = focal bits >> 20
#define LCAPG (2 * 65536)   // global per-image cell-list capacity
#define LCAP 10240       // LDS-cached list capacity (40 KB)
#define CHUNK 256
#define BUFC (CHUNK * CN)   // 5376 staged cells max per chunk

struct BlockAcc { float pos_sum; float bbox_sum; unsigned np; unsigned nn; };
struct ImgParams { double pos; double bbox; unsigned np, nn, k, ve, act; };

typedef float f4a __attribute__((ext_vector_type(4), aligned(4)));

// ---------- shared math: bit-identical across kernels (_rn-pinned, shared fns) ----------
__device__ __forceinline__ float box_area(float4 B) {
    return __fmul_rn(__fsub_rn(B.z, B.x), __fsub_rn(B.w, B.y));
}
__device__ __forceinline__ float iou_rcp(float4 A, float aa, float4 T, float ta) {
    float x1 = fmaxf(A.x, T.x), y1 = fmaxf(A.y, T.y);
    float x2 = fminf(A.z, T.z), y2 = fminf(A.w, T.w);
    float inter = __fmul_rn(fmaxf(__fsub_rn(x2, x1), 0.f), fmaxf(__fsub_rn(y2, y1), 0.f));
    float den = __fadd_rn(__fsub_rn(__fadd_rn(aa, ta), inter), 1e-6f);
    return __fmul_rn(inter, __builtin_amdgcn_rcpf(den));
}
__device__ __forceinline__ float row_prep_vals(float* __restrict__ c) {
    float m1[10];
#pragma unroll
    for (int j = 0; j < 10; ++j) m1[j] = fmaxf(c[j], c[j + 10]);
    float m2[5];
#pragma unroll
    for (int j = 0; j < 5; ++j) m2[j] = fmaxf(m1[j], m1[j + 5]);
    float ma = fmaxf(m2[0], m2[1]), mb = fmaxf(m2[2], m2[3]);
    float m = fmaxf(fmaxf(ma, mb), fmaxf(m2[4], c[20]));
#pragma unroll
    for (int j = 0; j < CN; ++j) c[j] = __expf(__fsub_rn(c[j], m));
    float s1[10];
#pragma unroll
    for (int j = 0; j < 10; ++j) s1[j] = __fadd_rn(c[j], c[j + 10]);
    float s2[5];
#pragma unroll
    for (int j = 0; j < 5; ++j) s2[j] = __fadd_rn(s1[j], s1[j + 5]);
    float sa = __fadd_rn(s2[0], s2[1]), sb = __fadd_rn(s2[2], s2[3]);
    float s = __fadd_rn(__fadd_rn(sa, sb), __fadd_rn(s2[4], c[20]));
    return __builtin_amdgcn_rcpf(s);
}
// vectorized row load: 5 x dwordx4 (4B-aligned ok on gfx950) + 1 dword
__device__ __forceinline__ float row_prep(const float* __restrict__ row, float* __restrict__ c) {
    const f4a* r4 = (const f4a*)row;
#pragma unroll
    for (int q = 0; q < 5; ++q) {
        f4a v = r4[q];
        c[q * 4 + 0] = v[0]; c[q * 4 + 1] = v[1];
        c[q * 4 + 2] = v[2]; c[q * 4 + 3] = v[3];
    }
    c[20] = row[20];
    return row_prep_vals(c);
}
__device__ __forceinline__ float cell_focal(float cexp, float inv, bool cellpos) {
    float p = __fmul_rn(cexp, inv);
    float pt = cellpos ? p : __fsub_rn(1.0f, p);
    float af = cellpos ? 0.25f : 0.75f;
    float om = __fsub_rn(1.0f, pt);
    float lg = __logf(fmaxf(pt, 1e-6f));
    return __fmul_rn(__fmul_rn(__fmul_rn(-af, om), om), lg);
}
__device__ __forceinline__ unsigned focal_bits(float fo) {
    unsigned bits = __float_as_uint(fo);
    if (bits == 0x80000000u) bits = 0u;   // canonicalize -0.0
    return bits;
}
__device__ __forceinline__ float bbox_per(float4 b1, float4 b2) {
    float x1 = fmaxf(b1.x, b2.x), y1 = fmaxf(b1.y, b2.y);
    float x2 = fminf(b1.z, b2.z), y2 = fminf(b1.w, b2.w);
    float inter = fmaxf(x2 - x1, 0.f) * fmaxf(y2 - y1, 0.f);
    float a1 = (b1.z - b1.x) * (b1.w - b1.y);
    float a2 = (b2.z - b2.x) * (b2.w - b2.y);
    float un = a1 + a2 - inter;
    float iou = inter / (un + 1e-6f);
    float ex1 = fminf(b1.x, b2.x), ey1 = fminf(b1.y, b2.y);
    float ex2 = fmaxf(b1.z, b2.z), ey2 = fmaxf(b1.w, b2.w);
    float enc = (ex2 - ex1) * (ey2 - ey1);
    float giou = iou - (enc - un) / (enc + 1e-6f);
    float gl = 1.0f - giou;
    float l1 = 0.f, d, ad;
    d = b1.x - b2.x; ad = fabsf(d); l1 += (ad < 1.f) ? (0.5f * d * d) : (ad - 0.5f);
    d = b1.y - b2.y; ad = fabsf(d); l1 += (ad < 1.f) ? (0.5f * d * d) : (ad - 0.5f);
    d = b1.z - b2.z; ad = fabsf(d); l1 += (ad < 1.f) ? (0.5f * d * d) : (ad - 0.5f);
    d = b1.w - b2.w; ad = fabsf(d); l1 += (ad < 1.f) ? (0.5f * d * d) : (ad - 0.5f);
    return gl + 0.5f * (l1 * 0.25f);
}
__device__ __forceinline__ unsigned mbcnt64(unsigned long long m) {
    return __builtin_amdgcn_mbcnt_hi((unsigned)(m >> 32),
           __builtin_amdgcn_mbcnt_lo((unsigned)m, 0u));
}

// ---------- fused main: match + force-argmax + focal + anchor hist ----------
__global__ __launch_bounds__(256) void main_kernel(
    const float* __restrict__ conf, const float4* __restrict__ bboxp,
    const float4* __restrict__ anchors, const float4* __restrict__ tboxes,
    const int* __restrict__ tlabels,
    unsigned long long* __restrict__ gbest,
    unsigned* __restrict__ ahist, unsigned* __restrict__ maxb,
    BlockAcc* __restrict__ blockAcc)
{
    __shared__ float4 tbS[TN];
    __shared__ int tlS[TN];
    __shared__ float taS[TN];
    __shared__ float iouS[16][260];        // HALF the IoU matrix (16 targets)
    __shared__ unsigned ahp[NBA / 2];      // packed 2 bins/u32
    __shared__ float pbV[TN][8];
    __shared__ int   pbA[TN][8];
    __shared__ float rF[2][4];
    __shared__ unsigned rI[2][4];
    int b = blockIdx.y, tid = threadIdx.x;
    int a = blockIdx.x * 256 + tid;
    for (int i = tid; i < NBA / 2; i += 256) ahp[i] = 0u;
    if (tid < TN) {
        float4 T = tboxes[b * TN + tid];
        tbS[tid] = T; tlS[tid] = tlabels[b * TN + tid]; taS[tid] = box_area(T);
    }
    float4 ab = anchors[a];
    float aa = box_area(ab);
    __syncthreads();

    // phases 1+2 chunked over targets (2 x 16): per-anchor running max
    // (ascending t, strict >) + per-target block-best via 8 partials of 32.
    float best = -1.0f; int bt = 0;
#pragma unroll
    for (int h = 0; h < 2; ++h) {
#pragma unroll
        for (int t2 = 0; t2 < 16; ++t2) {
            int t = h * 16 + t2;
            float iou = iou_rcp(ab, aa, tbS[t], taS[t]);
            iouS[t2][tid] = iou;
            if (iou > best) { best = iou; bt = t; }   // strict >: first occurrence
        }
        __syncthreads();
        if (tid < 128) {
            int t2 = tid & 15, pp = tid >> 4;        // pp in 0..7, 32 anchors each
            const float4* rp = (const float4*)(&iouS[t2][pp * 32]);
            float bv = -1.f; int ba = 0;
#pragma unroll
            for (int q = 0; q < 8; ++q) {
                float4 v4 = rp[q];
                int i0 = pp * 32 + q * 4;
                if (v4.x > bv) { bv = v4.x; ba = i0 + 0; }
                if (v4.y > bv) { bv = v4.y; ba = i0 + 1; }
                if (v4.z > bv) { bv = v4.z; ba = i0 + 2; }
                if (v4.w > bv) { bv = v4.w; ba = i0 + 3; }
            }
            pbV[h * 16 + t2][pp] = bv; pbA[h * 16 + t2][pp] = ba;
        }
        __syncthreads();   // protect iouS reuse by next chunk
    }
    if (tid < TN) {
        float bv = -1.f; int ba = 0;
#pragma unroll
        for (int pp = 0; pp < 8; ++pp) {
            float v = pbV[tid][pp];
            if (v > bv) { bv = v; ba = pbA[tid][pp]; }   // ascending anchor ranges
        }
        unsigned ga = blockIdx.x * 256 + (unsigned)ba;
        unsigned long long key =
            (((unsigned long long)__float_as_uint(bv)) << 32) | (unsigned long long)(unsigned)(~ga);
        atomicMax(&gbest[b * TN + tid], key);   // tie -> smaller anchor idx
    }

    // phase 3: focal (threshold classification; forced anchors fixed in tailA)
    size_t idx = (size_t)b * AN + a;
    bool posA = best >= 0.5f;
    bool negA = best < 0.4f;
    float fs = 0.f, bper = 0.f;
    unsigned mbenc = 0u;
    if (posA || negA) {
        float c[CN];
        float inv = row_prep(conf + idx * CN, c);
        if (posA) {
            int label = tlS[bt];
#pragma unroll
            for (int j = 0; j < CN; ++j) fs += cell_focal(c[j], inv, j == label);
            bper = bbox_per(bboxp[idx], tbS[bt]);
        } else {
            // neg: max_j focal_j == focal(max_j c_j), and max_j c_j == 1.0f
            // exactly (c[argmax] = exp(x_max - m) = exp(0); others <= 1.0f).
            float fo = cell_focal(1.0f, inv, false);
            unsigned mb = focal_bits(fo);
            mbenc = (mb << 1) | 1u;
            unsigned bin = mb >> 20;
            atomicAdd(&ahp[bin >> 1], 1u << ((bin & 1) << 4));
        }
    }
    maxb[idx] = mbenc;

    // block reduce {pos_sum, bbox_sum, np, nn} -> plain store
    float vpos = posA ? fs : 0.f, vb = bper;
    unsigned inp = posA ? 1u : 0u, inn = negA ? 1u : 0u;
#pragma unroll
    for (int off = 32; off; off >>= 1) {
        vpos += __shfl_down(vpos, off, 64);
        vb   += __shfl_down(vb,   off, 64);
        inp  += __shfl_down(inp,  off, 64);
        inn  += __shfl_down(inn,  off, 64);
    }
    int wv = tid >> 6, ln = tid & 63;
    if (ln == 0) { rF[0][wv] = vpos; rF[1][wv] = vb; rI[0][wv] = inp; rI[1][wv] = inn; }
    __syncthreads();
    if (tid == 0) {
        BlockAcc ba2;
        ba2.pos_sum = rF[0][0] + rF[0][1] + rF[0][2] + rF[0][3];
        ba2.bbox_sum = rF[1][0] + rF[1][1] + rF[1][2] + rF[1][3];
        ba2.np = rI[0][0] + rI[0][1] + rI[0][2] + rI[0][3];
        ba2.nn = rI[1][0] + rI[1][1] + rI[1][2] + rI[1][3];
        blockAcc[b * 256 + blockIdx.x] = ba2;
    }
    for (int i = tid; i < NBA / 2; i += 256) {
        unsigned v = ahp[i];
        if (v) {
            if (v & 0xFFFFu) atomicAdd(&ahist[b * NBA + 2 * i], v & 0xFFFFu);
            if (v >> 16)     atomicAdd(&ahist[b * NBA + 2 * i + 1], v >> 16);
        }
    }
}

// ---------- tailA: force-fix + totals + anchor-max threshold -> per-image params ----------
__global__ __launch_bounds__(1024) void tailA_kernel(
    const float* __restrict__ conf, const float4* __restrict__ bboxp,
    const float4* __restrict__ anchors, const float4* __restrict__ tboxes,
    const int* __restrict__ tlabels,
    const unsigned long long* __restrict__ gbest,
    const BlockAcc* __restrict__ blockAcc,
    const unsigned* __restrict__ ahist, unsigned* __restrict__ maxb,
    ImgParams* __restrict__ params)
{
    __shared__ unsigned hist[NBA];
    __shared__ unsigned scan_[1024];
    __shared__ unsigned gaS[TN];
    __shared__ float4 tbS[TN];
    __shared__ int tlS[TN];
    __shared__ float taS[TN];
    __shared__ float dps[TN], dbb[TN];
    __shared__ int dnp[TN], dnn[TN];
    __shared__ double sdbl[16];
    __shared__ unsigned suns[16];
    __shared__ double s_pos, s_bbox;
    __shared__ unsigned s_np, s_nn, s_k, s_act, s_ve;

    int b = blockIdx.x, tid = threadIdx.x;
    int wv = tid >> 6, ln = tid & 63;

    for (int i = tid; i < NBA; i += 1024) hist[i] = ahist[b * NBA + i];
    if (tid < TN) {
        gaS[tid] = ~(unsigned)(gbest[b * TN + tid] & 0xFFFFFFFFull);
        float4 T = tboxes[b * TN + tid];
        tbS[tid] = T; tlS[tid] = tlabels[b * TN + tid]; taS[tid] = box_area(T);
        dps[tid] = 0.f; dbb[tid] = 0.f; dnp[tid] = 0; dnn[tid] = 0;
    }
    __syncthreads();

    // ---- phase A: force-match fix (<=32 anchors) ----
    if (tid < TN) {
        bool doit = true;
        unsigned ga = gaS[tid];
        for (int u = 0; u < tid; ++u) if (gaS[u] == ga) doit = false;   // dedupe
        if (doit) {
            size_t idx = (size_t)b * AN + ga;
            float4 ab = anchors[ga];
            float aa = box_area(ab);
            float best = -1.f; int bt = 0;
#pragma unroll
            for (int t = 0; t < TN; ++t) {
                float iou = iou_rcp(ab, aa, tbS[t], taS[t]);   // bit-identical to main
                if (iou > best) { best = iou; bt = t; }
            }
            if (best < 0.5f) {
                int label = tlS[bt];
                float c[CN];
                float inv = row_prep(conf + idx * CN, c);
                float fsv = 0.f;
#pragma unroll
                for (int j = 0; j < CN; ++j) fsv += cell_focal(c[j], inv, j == label);
                dps[tid] = fsv;
                dbb[tid] = bbox_per(bboxp[idx], tbS[bt]);
                dnp[tid] = 1;
                if (best < 0.4f) {   // was counted neg: undo
                    unsigned enc = maxb[idx];
                    atomicSub(&hist[enc >> 21], 1u);
                    maxb[idx] = 0u;
                    dnn[tid] = -1;
                }
            }
        }
    }
    __syncthreads();

    // ---- phase B: totals ----
    if (tid < 256) {
        BlockAcc ba = blockAcc[b * 256 + tid];
        double ps = (double)ba.pos_sum, bs = (double)ba.bbox_sum;
        unsigned np = ba.np, nn = ba.nn;
#pragma unroll
        for (int off = 32; off; off >>= 1) {
            ps += __shfl_down(ps, off, 64);
            bs += __shfl_down(bs, off, 64);
            np += __shfl_down(np, off, 64);
            nn += __shfl_down(nn, off, 64);
        }
        if (ln == 0) { sdbl[wv] = ps; sdbl[8 + wv] = bs; suns[wv] = np; suns[8 + wv] = nn; }
    }
    __syncthreads();
    if (tid == 0) {
        double dp = 0, db = 0; int cp = 0, cn = 0;
        for (int i = 0; i < TN; ++i) { dp += dps[i]; db += dbb[i]; cp += dnp[i]; cn += dnn[i]; }
        s_pos = sdbl[0] + sdbl[1] + sdbl[2] + sdbl[3] + dp;
        s_bbox = sdbl[8] + sdbl[9] + sdbl[10] + sdbl[11] + db;
        unsigned NP = (unsigned)((int)(suns[0] + suns[1] + suns[2] + suns[3]) + cp);
        unsigned NN = (unsigned)((int)(suns[8] + suns[9] + suns[10] + suns[11]) + cn);
        s_np = NP; s_nn = NN;
        unsigned k = min(3u * NP, NN);
        s_k = k;
        s_act = (NN > 0 && k > 0) ? 1u : 0u;
        s_ve = 0u;
    }
    __syncthreads();

    if (s_act) {
        unsigned k = s_k;
        // ---- phase C: anchor-max threshold (2048 bins, 2/thread, suffix scan) ----
        unsigned lc0 = hist[tid * 2], lc1 = hist[tid * 2 + 1];
        unsigned cc = lc0 + lc1;
        scan_[tid] = cc;
        __syncthreads();
        for (int off = 1; off < 1024; off <<= 1) {
            unsigned v = (tid + off < 1024) ? scan_[tid + off] : 0u;
            __syncthreads();
            scan_[tid] += v;
            __syncthreads();
        }
        {
            unsigned above = (tid < 1023) ? scan_[tid + 1] : 0u;
            if (above < k && above + cc >= k) {
                unsigned bin = (above + lc1 >= k) ? (unsigned)(tid * 2 + 1) : (unsigned)(tid * 2);
                s_ve = (bin << 21) | 1u;
            }
        }
        __syncthreads();
    }
    if (tid == 0) {
        ImgParams P;
        P.pos = s_pos; P.bbox = s_bbox;
        P.np = s_np; P.nn = s_nn; P.k = s_k; P.ve = s_ve; P.act = s_act;
        params[b] = P;
    }
}

// ---------- tailB: parallel compact + focal rows ONCE -> cell-value list ----------
// grid (64, BN) x 256 threads: each block owns 1024 anchors of one image.
// LDS-staged append: cells collected in bufS, ONE global atomic per chunk.
__global__ __launch_bounds__(256) void tailB_kernel(
    const float* __restrict__ conf, const unsigned* __restrict__ maxb,
    const ImgParams* __restrict__ params,
    float* __restrict__ list, unsigned* __restrict__ listCnt)
{
    __shared__ int candS[1024];
    __shared__ unsigned bufS[BUFC];
    __shared__ unsigned s_cnt, s_bcnt, s_gbase;
    int b = blockIdx.y, tid = threadIdx.x;
    unsigned act = params[b].act;
    if (!act) return;
    unsigned ve = params[b].ve;
    unsigned vbits = ve >> 1;
    int base = blockIdx.x * 1024;

    if (tid == 0) s_cnt = 0u;
    __syncthreads();

    const uint4* mb4 = (const uint4*)(maxb + (size_t)b * AN + base);
    uint4 m4 = mb4[tid];
    unsigned c0 = (m4.x >= ve), c1 = (m4.y >= ve), c2 = (m4.z >= ve), c3 = (m4.w >= ve);
    unsigned cnt = c0 + c1 + c2 + c3;
    unsigned pos = 0;
    if (cnt) pos = atomicAdd(&s_cnt, cnt);
    int a0 = base + tid * 4;
    if (c0) candS[pos++] = a0 + 0;
    if (c1) candS[pos++] = a0 + 1;
    if (c2) candS[pos++] = a0 + 2;
    if (c3) candS[pos++] = a0 + 3;
    __syncthreads();
    unsigned n = s_cnt;

    for (unsigned cbase = 0; cbase < n; cbase += CHUNK) {
        if (tid == 0) s_bcnt = 0u;
        __syncthreads();
        unsigned i = cbase + tid;
        if (i < n) {
            int a = candS[i];
            size_t idx = (size_t)b * AN + a;
            float c[CN];
            float inv = row_prep(conf + idx * CN, c);
#pragma unroll
            for (int j = 0; j < CN; ++j) {
                float fo = cell_focal(c[j], inv, false);
                unsigned bits = focal_bits(fo);
                bool hit = bits >= vbits;
                unsigned long long msk = __ballot(hit);
                if (hit) {
                    unsigned pre = mbcnt64(msk);
                    unsigned bb = 0;
                    if (pre == 0) bb = atomicAdd(&s_bcnt, (unsigned)__popcll(msk));
                    bb = __shfl(bb, (int)(__ffsll((long long)msk) - 1), 64);
                    bufS[bb + pre] = bits;   // canonicalized focal bits
                }
            }
        }
        __syncthreads();
        unsigned ccnt = s_bcnt;
        if (ccnt) {
            if (tid == 0) s_gbase = atomicAdd(&listCnt[b * 16], ccnt);  // 64B-padded counter
            __syncthreads();
            unsigned gb = s_gbase;
            for (unsigned j2 = tid; j2 < ccnt; j2 += 256) {
                unsigned p = gb + j2;
                if (p < (unsigned)LCAPG)
                    list[(size_t)b * LCAPG + p] = __uint_as_float(bufS[j2]);
            }
        }
        __syncthreads();
    }
}

// ---------- tailC: top-k select over compact list + per-image result + average ----------
__global__ __launch_bounds__(1024) void tailC_kernel(
    const float* __restrict__ list, const unsigned* __restrict__ listCnt,
    const ImgParams* __restrict__ params,
    double* __restrict__ imgRes, unsigned* __restrict__ ctr,
    float* __restrict__ out)
{
    __shared__ float lcache[LCAP];      // 40 KB
    __shared__ unsigned hist[4096];
    __shared__ unsigned scan_[1024];
    __shared__ double sdbl[16];
    __shared__ double s_sumAbove;
    __shared__ unsigned s_b1, s_rem, s_b2, s_rem2, s_b3, s_rem3;

    int b = blockIdx.x, tid = threadIdx.x;
    int wv = tid >> 6, ln = tid & 63;
    ImgParams P = params[b];
    double topk = 0.0;

    if (P.act) {
        unsigned n = min(listCnt[b * 16], (unsigned)LCAPG);
        const float* gl = list + (size_t)b * LCAPG;
        bool inL = (n <= (unsigned)LCAP);
        if (inL) for (unsigned i = tid; i < n; i += 1024) lcache[i] = gl[i];
        if (tid == 0) { s_b1 = 0; s_rem = 0; s_b3 = 0; s_rem3 = 0; }
        for (int i = tid; i < 4096; i += 1024) hist[i] = 0u;
        __syncthreads();

        // pass 0: 2048-bin hist over top bits (focal >= 0 -> bits>>20 < 2048)
        for (unsigned i = tid; i < n; i += 1024) {
            unsigned bits = __float_as_uint(inL ? lcache[i] : gl[i]);
            atomicAdd(&hist[bits >> 20], 1u);
        }
        __syncthreads();

        // select b1 (suffix scan, 2 bins/thread)
        unsigned lc0 = hist[tid * 2], lc1 = hist[tid * 2 + 1];
        unsigned cc = lc0 + lc1;
        scan_[tid] = cc;
        __syncthreads();
        for (int off = 1; off < 1024; off <<= 1) {
            unsigned v = (tid + off < 1024) ? scan_[tid + off] : 0u;
            __syncthreads();
            scan_[tid] += v;
            __syncthreads();
        }
        {
            unsigned total = scan_[0];
            unsigned above = (tid < 1023) ? scan_[tid + 1] : 0u;
            unsigned r = min(P.k, total);
            if (r > 0 && above < r && above + cc >= r) {
                if (above + lc1 >= r) { s_b1 = (unsigned)(tid * 2 + 1); s_rem = r - above; }
                else { s_b1 = (unsigned)(tid * 2); s_rem = r - above - lc1; }
            }
        }
        __syncthreads();
        unsigned b1 = s_b1, rem = s_rem;

        // pass 1: sumAbove (hi > b1) + 12-bit sub-hist for hi == b1
        for (int i = tid; i < 4096; i += 1024) hist[i] = 0u;
        __syncthreads();
        double sA = 0.0;
        for (unsigned i = tid; i < n; i += 1024) {
            float v = inL ? lcache[i] : gl[i];
            unsigned bits = __float_as_uint(v);
            unsigned hi = bits >> 20;
            if (hi > b1) sA += (double)v;
            else if (hi == b1) atomicAdd(&hist[(bits >> 8) & 0xFFFu], 1u);
        }
#pragma unroll
        for (int off = 32; off; off >>= 1) sA += __shfl_down(sA, off, 64);
        if (ln == 0) sdbl[wv] = sA;
        __syncthreads();
        if (tid == 0) {
            double tt = 0;
            for (int w = 0; w < 16; ++w) tt += sdbl[w];
            s_sumAbove = tt;
        }
        __syncthreads();
        double sumAbove = s_sumAbove;

        if (rem == 0) {
            topk = sumAbove;
        } else {
            // select b2 from 4096-bin hist (4 bins/thread)
            unsigned l4[4], cc4 = 0;
#pragma unroll
            for (int q = 0; q < 4; ++q) { l4[q] = hist[tid * 4 + q]; cc4 += l4[q]; }
            scan_[tid] = cc4;
            __syncthreads();
            for (int off = 1; off < 1024; off <<= 1) {
                unsigned v = (tid + off < 1024) ? scan_[tid + off] : 0u;
                __syncthreads();
                scan_[tid] += v;
                __syncthreads();
            }
            {
                unsigned total = scan_[0];
                unsigned above = (tid < 1023) ? scan_[tid + 1] : 0u;
                unsigned r = min(rem, total);
                if (above < r && above + cc4 >= r) {
                    unsigned a2 = above;
                    for (int i = 3; i >= 0; --i) {
                        unsigned bc = l4[i];
                        if (a2 + bc >= r) { s_b2 = (unsigned)(tid * 4 + i); s_rem2 = r - a2; break; }
                        a2 += bc;
                    }
                }
            }
            __syncthreads();
            unsigned b2 = s_b2, rem2 = s_rem2;
            if (tid < 256) hist[tid] = 0u;
            __syncthreads();

            // pass 2: sMid (sub > b2) + 8-bit hist for sub == b2
            double sMid = 0.0;
            for (unsigned i = tid; i < n; i += 1024) {
                float v = inL ? lcache[i] : gl[i];
                unsigned bits = __float_as_uint(v);
                if ((bits >> 20) != b1) continue;
                unsigned sub = (bits >> 8) & 0xFFFu;
                if (sub > b2) sMid += (double)v;
                else if (sub == b2) atomicAdd(&hist[bits & 0xFFu], 1u);
            }
            __syncthreads();
            if (tid < 256) scan_[tid] = hist[tid];
            __syncthreads();
            for (int off = 1; off < 256; off <<= 1) {
                unsigned v = 0;
                if (tid < 256 && tid + off < 256) v = scan_[tid + off];
                __syncthreads();
                if (tid < 256) scan_[tid] += v;
                __syncthreads();
            }
            if (tid < 256) {
                unsigned above8 = (tid < 255) ? scan_[tid + 1] : 0u;
                unsigned c8 = hist[tid];
                if (above8 < rem2 && above8 + c8 >= rem2) { s_b3 = (unsigned)tid; s_rem3 = rem2 - above8; }
            }
            __syncthreads();
            unsigned b3 = s_b3, rem3 = s_rem3;

            // pass 3: s3 for (b1,b2, low > b3)
            double s3 = 0.0;
            for (unsigned i = tid; i < n; i += 1024) {
                float v = inL ? lcache[i] : gl[i];
                unsigned bits = __float_as_uint(v);
                if ((bits >> 20) == b1 && ((bits >> 8) & 0xFFFu) == b2 && (bits & 0xFFu) > b3)
                    s3 += (double)v;
            }
            double tot = sMid + s3;
#pragma unroll
            for (int off = 32; off; off >>= 1) tot += __shfl_down(tot, off, 64);
            if (ln == 0) sdbl[wv] = tot;
            __syncthreads();
            if (tid == 0) {
                double totAll = 0;
                for (int w = 0; w < 16; ++w) totAll += sdbl[w];
                unsigned vb3 = (b1 << 20) | (b2 << 8) | b3;
                topk = sumAbove + totAll + (double)rem3 * (double)__uint_as_float(vb3);
            }
        }
    }

    // ---- per-image result + last-block average ----
    if (tid == 0) {
        double confl;
        if (P.act) confl = (P.pos + topk) / (double)max(P.np + P.k, 1u);
        else       confl = P.pos / (double)max(P.np, 1u);
        imgRes[b * 2 + 0] = confl;
        imgRes[b * 2 + 1] = P.bbox / (double)max(P.np, 1u);
        __threadfence();
        unsigned prev = atomicAdd(ctr, 1u);
        if (prev == BN - 1) {
            __threadfence();
            double cs = 0, bs = 0;
            for (int i = 0; i < BN; ++i) { cs += imgRes[i * 2]; bs += imgRes[i * 2 + 1]; }
            cs /= BN; bs /= BN;
            out[0] = (float)(cs + bs);
            out[1] = (float)cs;
            out[2] = (float)bs;
        }
    }
}

extern "C" void kernel_launch(void* const* d_in, const int* in_sizes, int n_in,
                              void* d_out, int out_size, void* d_ws, size_t ws_size,
                              hipStream_t stream)
{
    (void)in_sizes; (void)n_in; (void)out_size; (void)ws_size;
    const float*  conf    = (const float*)d_in[0];
    const float4* bboxp   = (const float4*)d_in[1];
    const float4* anchors = (const float4*)d_in[2];
    const float4* tboxes  = (const float4*)d_in[3];
    const int*    tlabels = (const int*)d_in[4];
    float* out = (float*)d_out;
    char* ws = (char*)d_ws;
    size_t off = 0;
    auto alloc = [&](size_t bytes) -> void* {
        void* p = (void*)(ws + off);
        off = (off + bytes + 255) & ~(size_t)255;
        return p;
    };
    unsigned*  maxb     = (unsigned*)alloc((size_t)BN * AN * 4);
    float*     list     = (float*)alloc((size_t)BN * LCAPG * 4);
    BlockAcc*  blockAcc = (BlockAcc*)alloc((size_t)BN * 256 * sizeof(BlockAcc));
    double*    imgRes   = (double*)alloc((size_t)BN * 2 * 8);
    ImgParams* params   = (ImgParams*)alloc((size_t)BN * sizeof(ImgParams));
    size_t zstart = off;
    unsigned long long* gbest = (unsigned long long*)alloc((size_t)BN * TN * 8);
    unsigned* ahist   = (unsigned*)alloc((size_t)BN * NBA * 4);
    unsigned* ctr     = (unsigned*)alloc(256);
    unsigned* listCnt = (unsigned*)alloc((size_t)BN * 16 * 4);   // 64B stride per image
    size_t zbytes = off - zstart;
    hipMemsetAsync(ws + zstart, 0, zbytes, stream);

    dim3 gridA(AN / 256, BN);
    main_kernel<<<gridA, 256, 0, stream>>>(conf, bboxp, anchors, tboxes, tlabels,
                                           gbest, ahist, maxb, blockAcc);
    tailA_kernel<<<BN, 1024, 0, stream>>>(conf, bboxp, anchors, tboxes, tlabels,
                                          gbest, blockAcc, ahist, maxb, params);
    tailB_kernel<<<dim3(64, BN), 256, 0, stream>>>(conf, maxb, params, list, listCnt);
    tailC_kernel<<<BN, 1024, 0, stream>>>(list, listCnt, params, imgRes, ctr, out);
}